// Round 9
// baseline (162.410 us; speedup 1.0000x reference)
//
#include <hip/hip_runtime.h>
#include <stdint.h>
#include <stddef.h>

#define B_ROWS 8192
#define NX 2048
#define NH 512
#define NY 1024

// prep kernel block split: elementwise cast blocks, then wq blocks
#define X_ELEMS (B_ROWS * NX)                 // 16777216 (relu+cast)
#define EW_ELEMS (X_ELEMS + NH * NX)          // + 1048576 (plain cast)
#define EW_BLOCKS (EW_ELEMS / (8 * 256))      // 8704
#define WQ_BLOCKS (NY / 4)                    // 256

typedef __attribute__((ext_vector_type(8))) short bf16x8;
typedef __attribute__((ext_vector_type(4))) float f32x4;

static __device__ __forceinline__ unsigned short f2bf(float f) {
    union { float f; unsigned int u; } c; c.f = f;
    unsigned int r = 0x7FFFu + ((c.u >> 16) & 1u);
    return (unsigned short)((c.u + r) >> 16);
}

static __device__ __forceinline__ void glld16(const void* g, void* l) {
    __builtin_amdgcn_global_load_lds(
        (const __attribute__((address_space(1))) unsigned int*)g,
        (__attribute__((address_space(3))) unsigned int*)l, 16, 0, 0);
}

// ---------------- prep: relu(x)->bf16, W_fc->bf16, W_q->bf16+rowsq, hsq=0 ----------------
__global__ __launch_bounds__(256) void prep_kernel(const float* __restrict__ x,
                                                   const float* __restrict__ wfc,
                                                   const float* __restrict__ wq,
                                                   unsigned short* __restrict__ xb,
                                                   unsigned short* __restrict__ wfcb,
                                                   unsigned short* __restrict__ wqb,
                                                   float* __restrict__ wqsq,
                                                   float* __restrict__ hsq) {
    const int bid = blockIdx.x;
    const int tid = threadIdx.x;
    if (bid < EW_BLOCKS) {
        size_t idx = ((size_t)bid * 256 + tid) * 8;
        if (idx < (size_t)X_ELEMS) {
            float4 a = *(const float4*)&x[idx];
            float4 b = *(const float4*)&x[idx + 4];
            bf16x8 o;
            o[0] = (short)f2bf(fmaxf(a.x, 0.f)); o[1] = (short)f2bf(fmaxf(a.y, 0.f));
            o[2] = (short)f2bf(fmaxf(a.z, 0.f)); o[3] = (short)f2bf(fmaxf(a.w, 0.f));
            o[4] = (short)f2bf(fmaxf(b.x, 0.f)); o[5] = (short)f2bf(fmaxf(b.y, 0.f));
            o[6] = (short)f2bf(fmaxf(b.z, 0.f)); o[7] = (short)f2bf(fmaxf(b.w, 0.f));
            *(bf16x8*)&xb[idx] = o;
        } else {
            size_t off = idx - X_ELEMS;
            float4 a = *(const float4*)&wfc[off];
            float4 b = *(const float4*)&wfc[off + 4];
            bf16x8 o;
            o[0] = (short)f2bf(a.x); o[1] = (short)f2bf(a.y);
            o[2] = (short)f2bf(a.z); o[3] = (short)f2bf(a.w);
            o[4] = (short)f2bf(b.x); o[5] = (short)f2bf(b.y);
            o[6] = (short)f2bf(b.z); o[7] = (short)f2bf(b.w);
            *(bf16x8*)&wfcb[off] = o;
        }
    } else {
        const int b2 = bid - EW_BLOCKS;        // 0..255
        const int lane = tid & 63;
        const int row = b2 * 4 + (tid >> 6);
        const float* p = wq + (size_t)row * NH + lane * 8;
        float4 a = *(const float4*)p;
        float4 b = *(const float4*)(p + 4);
        bf16x8 o;
        o[0] = (short)f2bf(a.x); o[1] = (short)f2bf(a.y);
        o[2] = (short)f2bf(a.z); o[3] = (short)f2bf(a.w);
        o[4] = (short)f2bf(b.x); o[5] = (short)f2bf(b.y);
        o[6] = (short)f2bf(b.z); o[7] = (short)f2bf(b.w);
        *(bf16x8*)&wqb[(size_t)row * NH + lane * 8] = o;
        float s = a.x*a.x + a.y*a.y + a.z*a.z + a.w*a.w
                + b.x*b.x + b.y*b.y + b.z*b.z + b.w*b.w;
        #pragma unroll
        for (int off = 32; off > 0; off >>= 1) s += __shfl_xor(s, off);
        if (lane == 0) wqsq[row] = s;
        if (tid < 32) hsq[b2 * 32 + tid] = 0.0f;   // zero-init for gemm1 atomics
    }
}

// ---------------- GEMM1: h = relu(xb @ wfcb^T + b) -> bf16 hb, fused hsq ----------------
// R8 post-mortem: 32x32 wave-tiles = 1.0 ds_read/MFMA -> LDS-read-bound ~10x
// over MFMA floor. R9: back to R0's proven 128x128 tile, 2-way in-block
// split-K, 4 waves/group of WAVE-TILE 64x64 (acc 4x4 = 0.5 reads/MFMA, halves
// LDS traffic), with R7's counted-vmcnt schedule: BK=32, THREE buffers,
// 2-deep prefetch, uniform 4 glld16/wave/iter:
//   {vmcnt(4) [stage(it) landed] -> s_barrier -> stage(it+2) into buf
//    (it+2)%3 [last read at it-1, safe] -> compute(it)}.
// vmcnt->0 only at the final iteration. Grid 256 (1 block/CU), 512 thr,
// LDS 96 KiB. Fragment/stage swizzles and split-K epilogue verbatim from R0.
__global__ __launch_bounds__(512, 2) void gemm1_kernel(const unsigned short* __restrict__ xb,
                                                       const unsigned short* __restrict__ wfcb,
                                                       const float* __restrict__ b_fc,
                                                       unsigned short* __restrict__ hb,
                                                       float* __restrict__ hsq) {
    __shared__ unsigned char smem[98304];
    unsigned char* AsB = smem;               // [g][buf][128 rows][64 B] = 2x3x8 KiB
    unsigned char* BsB = smem + 49152;       // [g][buf][128 rows][64 B] = 2x3x8 KiB

    const int tid = threadIdx.x;
    const int lane = tid & 63;
    const int grp = tid >> 8;                // k-half 0/1
    const int wave = (tid >> 6) & 3;         // wave within group
    const int wm = wave >> 1, wn = wave & 1;
    const int quad = lane >> 4;
    const int r = lane & 15;

    // bid = c(3b XCD) | q(5b): n-tile = q&3, m-tile = c*8 + (q>>2)
    const int bid = blockIdx.x;              // 0..255
    const int c_ = bid & 7, q_ = bid >> 3;
    const int n0 = (q_ & 3) * 128;
    const int m0 = ((c_ << 3) | (q_ >> 2)) * 128;
    const int kbase = grp * (NX / 2);

    f32x4 acc[4][4];
    #pragma unroll
    for (int i = 0; i < 4; ++i)
        #pragma unroll
        for (int j = 0; j < 4; ++j) acc[i][j] = (f32x4)(0.0f);

    const int lrow = lane >> 2;                       // 0..15 (row within 16-row chunk)
    const int gch = (lane & 3) ^ ((lrow >> 1) & 3);   // swizzled 16B chunk
    const int fsw = (quad ^ ((r >> 1) & 3)) * 16;     // fragment chunk byte offset

    const char* asrc = (const char*)xb +
        (size_t)(m0 + wave * 32 + lrow) * (NX * 2) + (size_t)kbase * 2 + gch * 16;
    const char* bsrc = (const char*)wfcb +
        (size_t)(n0 + wave * 32 + lrow) * (NX * 2) + (size_t)kbase * 2 + gch * 16;

    auto stage = [&](int bi, int k0) {                // 4 loads per wave, uniform
        const int sb = grp * 24576 + bi * 8192;
        #pragma unroll
        for (int c = 0; c < 2; ++c) {
            glld16(asrc + (size_t)k0 * 2 + (size_t)c * (16 * NX * 2),
                   AsB + sb + (wave * 32 + c * 16) * 64);
            glld16(bsrc + (size_t)k0 * 2 + (size_t)c * (16 * NX * 2),
                   BsB + sb + (wave * 32 + c * 16) * 64);
        }
    };

    stage(0, 0);
    stage(1, 32);

    int cb = 0, sb2 = 2;
    #pragma unroll 1
    for (int it = 0; it < 32; ++it) {                 // 32 iters per k-half
        if (it == 31) { asm volatile("s_waitcnt vmcnt(0)" ::: "memory"); }
        else          { asm volatile("s_waitcnt vmcnt(4)" ::: "memory"); }
        __builtin_amdgcn_sched_barrier(0);
        __builtin_amdgcn_s_barrier();
        __builtin_amdgcn_sched_barrier(0);
        if (it + 2 < 32) stage(sb2, it * 32 + 64);
        __builtin_amdgcn_sched_barrier(0);
        const unsigned char* ab = AsB + grp * 24576 + cb * 8192;
        const unsigned char* bb = BsB + grp * 24576 + cb * 8192;
        bf16x8 af[4], bfv[4];
        #pragma unroll
        for (int i = 0; i < 4; ++i)
            af[i] = *(const bf16x8*)(ab + (wm * 64 + i * 16 + r) * 64 + fsw);
        #pragma unroll
        for (int j = 0; j < 4; ++j)
            bfv[j] = *(const bf16x8*)(bb + (wn * 64 + j * 16 + r) * 64 + fsw);
        #pragma unroll
        for (int i = 0; i < 4; ++i)
            #pragma unroll
            for (int j = 0; j < 4; ++j)
                acc[i][j] = __builtin_amdgcn_mfma_f32_16x16x32_bf16(af[i], bfv[j], acc[i][j], 0, 0, 0);
        cb = (cb == 2) ? 0 : cb + 1;
        sb2 = (sb2 == 2) ? 0 : sb2 + 1;
    }

    // ---- combine the two k-halves through LDS, epilogue by group 0 (R0 scheme) ----
    float* smemF = (float*)smem;
    __syncthreads();
    if (grp == 1) {
        #pragma unroll
        for (int i = 0; i < 4; ++i) {
            #pragma unroll
            for (int j = 0; j < 4; ++j) {
                int cl = wn * 64 + j * 16 + r;
                int rowb = wm * 64 + i * 16 + quad * 4;
                *(f32x4*)(smemF + cl * 128 + (rowb ^ ((cl & 7) << 2))) = acc[i][j];
            }
        }
    }
    __syncthreads();
    if (grp == 0) {
        float p[4][4];
        #pragma unroll
        for (int i = 0; i < 4; ++i)
            #pragma unroll
            for (int rr = 0; rr < 4; ++rr) p[i][rr] = 0.0f;

        #pragma unroll
        for (int i = 0; i < 4; ++i) {
            #pragma unroll
            for (int j = 0; j < 4; ++j) {
                int cl = wn * 64 + j * 16 + r;
                int rowb = wm * 64 + i * 16 + quad * 4;
                f32x4 o = *(const f32x4*)(smemF + cl * 128 + (rowb ^ ((cl & 7) << 2)));
                int col = n0 + cl;
                float bias = b_fc[col];
                #pragma unroll
                for (int rr = 0; rr < 4; ++rr) {
                    float v = fmaxf(acc[i][j][rr] + o[rr] + bias, 0.0f);
                    hb[(size_t)(m0 + rowb + rr) * NH + col] = f2bf(v);
                    p[i][rr] += v * v;
                }
            }
        }
        #pragma unroll
        for (int mask = 1; mask < 16; mask <<= 1) {
            #pragma unroll
            for (int i = 0; i < 4; ++i)
                #pragma unroll
                for (int rr = 0; rr < 4; ++rr)
                    p[i][rr] += __shfl_xor(p[i][rr], mask);
        }
        if (r == 0) {
            #pragma unroll
            for (int i = 0; i < 4; ++i)
                #pragma unroll
                for (int rr = 0; rr < 4; ++rr)
                    atomicAdd(&hsq[m0 + wm * 64 + i * 16 + quad * 4 + rr], p[i][rr]);
        }
    }
}

// ---------------- GEMM2 fused with per-row LSE (single pass over out) ----------------
// NU=1  =>  t = -log1p(d)  =>  exp(t) = 1/(1+d): softmax denominator is a v_rcp.
// M=32 x N=1024 (in-block LSE), grid 256 = 1 block/CU. Barrier-free K-loop
// (B staging wave-private, A staged once), 1024 threads = 16 waves = 4
// waves/SIMD, each a private {issue 4 glld16; vmcnt(4); compute} pipeline.
// Wave w owns cols [w*64,+64): acc 2x4. A 32 KiB staged once + B 2x64 KiB.
// s_setprio(1) around the MFMA cluster (T5: waves drift).
__global__ __launch_bounds__(1024, 4) void gemm2_kernel(const unsigned short* __restrict__ hb,
                                                        const unsigned short* __restrict__ wqb,
                                                        const float* __restrict__ hsq,
                                                        const float* __restrict__ wqsq,
                                                        float* __restrict__ out) {
    __shared__ unsigned char smem[163840];
    char* As = (char*)smem;                  // [16 slabs][32 rows][64 B] = 32 KiB (staged once)
    char* Bs = (char*)smem + 32768;          // [buf][1024 rows][64 B] = 2 x 64 KiB

    const int tid = threadIdx.x;
    const int lane = tid & 63;
    const int wave = tid >> 6;               // 0..15 -> col slab [wave*64, +64)
    const int quad = lane >> 4;
    const int r = lane & 15;
    const int m0 = blockIdx.x * 32;          // 256 blocks

    f32x4 acc[2][4];
    #pragma unroll
    for (int i = 0; i < 2; ++i)
        #pragma unroll
        for (int j = 0; j < 4; ++j) acc[i][j] = (f32x4)(0.0f);

    const int lrow = lane >> 2;                       // 0..15
    const int gch = (lane & 3) ^ ((lrow >> 1) & 3);   // swizzled 16B chunk
    const int fsw = (quad ^ ((r >> 1) & 3)) * 16;

    const char* bsrc = (const char*)wqb + (size_t)(wave * 64 + lrow) * (NH * 2) + gch * 16;

    auto stageB = [&](int buf, int k0) {
        #pragma unroll
        for (int c = 0; c < 4; ++c)                   // this wave's 64 B-rows
            glld16(bsrc + (size_t)(c * 16 * NH + k0) * 2,
                   Bs + buf * 65536 + (wave * 64 + c * 16) * 64);
    };

    // ---- prologue: wave w stages A k-slab w (2 glld16) + its B(0) rows ----
    #pragma unroll
    for (int half = 0; half < 2; ++half)
        glld16((const char*)hb + (size_t)(m0 + half * 16 + lrow) * (NH * 2) + wave * 64 + gch * 16,
               As + wave * 2048 + half * 1024);
    stageB(0, 0);
    asm volatile("s_waitcnt vmcnt(4)" ::: "memory");  // A landed; B(0) may fly
    __builtin_amdgcn_sched_barrier(0);
    __builtin_amdgcn_s_barrier();
    __builtin_amdgcn_sched_barrier(0);

    #pragma unroll 1
    for (int it = 0; it < NH / 32; ++it) {            // 16 iters, NO barriers
        if (it + 1 < NH / 32) stageB((it + 1) & 1, it * 32 + 32);
        __builtin_amdgcn_sched_barrier(0);
        if (it == NH / 32 - 1) { asm volatile("s_waitcnt vmcnt(0)" ::: "memory"); }
        else                   { asm volatile("s_waitcnt vmcnt(4)" ::: "memory"); }
        __builtin_amdgcn_sched_barrier(0);
        const char* ab = As + it * 2048;
        const char* bb = Bs + (it & 1) * 65536;
        bf16x8 af[2], bfv[4];
        #pragma unroll
        for (int i = 0; i < 2; ++i)
            af[i] = *(const bf16x8*)(ab + (i * 16 + r) * 64 + fsw);
        #pragma unroll
        for (int j = 0; j < 4; ++j)
            bfv[j] = *(const bf16x8*)(bb + (wave * 64 + j * 16 + r) * 64 + fsw);
        __builtin_amdgcn_s_setprio(1);
        #pragma unroll
        for (int i = 0; i < 2; ++i)
            #pragma unroll
            for (int j = 0; j < 4; ++j)
                acc[i][j] = __builtin_amdgcn_mfma_f32_16x16x32_bf16(af[i], bfv[j], acc[i][j], 0, 0, 0);
        __builtin_amdgcn_s_setprio(0);
    }

    // ---- epilogue: d, t, row-sums of exp(t) = 1/(1+d), LSE, store ----
    float hs_[2][4];
    #pragma unroll
    for (int i = 0; i < 2; ++i)
        #pragma unroll
        for (int rr = 0; rr < 4; ++rr)
            hs_[i][rr] = hsq[m0 + i * 16 + quad * 4 + rr];

    float srow[2][4];
    #pragma unroll
    for (int i = 0; i < 2; ++i)
        #pragma unroll
        for (int rr = 0; rr < 4; ++rr) srow[i][rr] = 0.0f;

    #pragma unroll
    for (int j = 0; j < 4; ++j) {
        float wqv = wqsq[wave * 64 + j * 16 + r];
        #pragma unroll
        for (int i = 0; i < 2; ++i) {
            #pragma unroll
            for (int rr = 0; rr < 4; ++rr) {
                float d = hs_[i][rr] - 2.0f * acc[i][j][rr] + wqv;
                d = fmaxf(d, 0.0f);
                float onepd = 1.0f + d;
                srow[i][rr] += __builtin_amdgcn_rcpf(onepd);
                acc[i][j][rr] = -__logf(onepd);       // keep t in-register
            }
        }
    }
    #pragma unroll
    for (int mask = 1; mask < 16; mask <<= 1)
        #pragma unroll
        for (int i = 0; i < 2; ++i)
            #pragma unroll
            for (int rr = 0; rr < 4; ++rr)
                srow[i][rr] += __shfl_xor(srow[i][rr], mask);

    float* smemF = (float*)smem;                      // reuse As region
    __syncthreads();                                  // ALL waves out of K-loop first
    if (r == 0) {
        #pragma unroll
        for (int i = 0; i < 2; ++i)
            #pragma unroll
            for (int rr = 0; rr < 4; ++rr)
                smemF[wave * 32 + i * 16 + quad * 4 + rr] = srow[i][rr];
    }
    __syncthreads();
    if (tid < 32) {
        float S = 0.0f;
        #pragma unroll
        for (int w = 0; w < 16; ++w) S += smemF[w * 32 + tid];
        smemF[512 + tid] = __logf(S);
    }
    __syncthreads();

    #pragma unroll
    for (int i = 0; i < 2; ++i) {
        #pragma unroll
        for (int rr = 0; rr < 4; ++rr) {
            float l = smemF[512 + i * 16 + quad * 4 + rr];
            size_t rowoff = (size_t)(m0 + i * 16 + quad * 4 + rr) * NY + wave * 64 + r;
            #pragma unroll
            for (int j = 0; j < 4; ++j)
                out[rowoff + j * 16] = acc[i][j][rr] - l;
        }
    }
}

extern "C" void kernel_launch(void* const* d_in, const int* in_sizes, int n_in,
                              void* d_out, int out_size, void* d_ws, size_t ws_size,
                              hipStream_t stream) {
    const float* x    = (const float*)d_in[0];
    const float* W_fc = (const float*)d_in[1];
    const float* b_fc = (const float*)d_in[2];
    const float* W_q  = (const float*)d_in[3];
    float* out = (float*)d_out;

    char* ws = (char*)d_ws;
    unsigned short* xb   = (unsigned short*)(ws);                        // 32 MiB
    unsigned short* wfcb = (unsigned short*)(ws + 33554432);             // 2 MiB
    unsigned short* wqb  = (unsigned short*)(ws + 35651584);             // 1 MiB
    float*          wqsq = (float*)(ws + 36700160);                      // 4 KiB
    unsigned short* hb   = (unsigned short*)(ws + 36704256);             // 8 MiB
    float*          hsq  = (float*)(ws + 45092864);                      // 32 KiB

    prep_kernel<<<EW_BLOCKS + WQ_BLOCKS, 256, 0, stream>>>(x, W_fc, W_q, xb, wfcb, wqb, wqsq, hsq);
    gemm1_kernel<<<256, 512, 0, stream>>>(xb, wfcb, b_fc, hb, hsq);
    gemm2_kernel<<<B_ROWS / 32, 1024, 0, stream>>>(hb, wqb, hsq, wqsq, out);
}

// Round 10
// 158.418 us; speedup vs baseline: 1.0252x; 1.0252x over previous
//
#include <hip/hip_runtime.h>
#include <stdint.h>
#include <stddef.h>

#define B_ROWS 8192
#define NX 2048
#define NH 512
#define NY 1024

// prep kernel block split: elementwise cast blocks, then wq blocks
#define X_ELEMS (B_ROWS * NX)                 // 16777216 (relu+cast)
#define EW_ELEMS (X_ELEMS + NH * NX)          // + 1048576 (plain cast)
#define EW_BLOCKS (EW_ELEMS / (8 * 256))      // 8704
#define WQ_BLOCKS (NY / 4)                    // 256

typedef __attribute__((ext_vector_type(8))) short bf16x8;
typedef __attribute__((ext_vector_type(4))) float f32x4;

static __device__ __forceinline__ unsigned short f2bf(float f) {
    union { float f; unsigned int u; } c; c.f = f;
    unsigned int r = 0x7FFFu + ((c.u >> 16) & 1u);
    return (unsigned short)((c.u + r) >> 16);
}

static __device__ __forceinline__ void glld16(const void* g, void* l) {
    __builtin_amdgcn_global_load_lds(
        (const __attribute__((address_space(1))) unsigned int*)g,
        (__attribute__((address_space(3))) unsigned int*)l, 16, 0, 0);
}

// ---------------- prep: relu(x)->bf16, W_fc->bf16, W_q->bf16+rowsq, hsq=0 ----------------
__global__ __launch_bounds__(256) void prep_kernel(const float* __restrict__ x,
                                                   const float* __restrict__ wfc,
                                                   const float* __restrict__ wq,
                                                   unsigned short* __restrict__ xb,
                                                   unsigned short* __restrict__ wfcb,
                                                   unsigned short* __restrict__ wqb,
                                                   float* __restrict__ wqsq,
                                                   float* __restrict__ hsq) {
    const int bid = blockIdx.x;
    const int tid = threadIdx.x;
    if (bid < EW_BLOCKS) {
        size_t idx = ((size_t)bid * 256 + tid) * 8;
        if (idx < (size_t)X_ELEMS) {
            float4 a = *(const float4*)&x[idx];
            float4 b = *(const float4*)&x[idx + 4];
            bf16x8 o;
            o[0] = (short)f2bf(fmaxf(a.x, 0.f)); o[1] = (short)f2bf(fmaxf(a.y, 0.f));
            o[2] = (short)f2bf(fmaxf(a.z, 0.f)); o[3] = (short)f2bf(fmaxf(a.w, 0.f));
            o[4] = (short)f2bf(fmaxf(b.x, 0.f)); o[5] = (short)f2bf(fmaxf(b.y, 0.f));
            o[6] = (short)f2bf(fmaxf(b.z, 0.f)); o[7] = (short)f2bf(fmaxf(b.w, 0.f));
            *(bf16x8*)&xb[idx] = o;
        } else {
            size_t off = idx - X_ELEMS;
            float4 a = *(const float4*)&wfc[off];
            float4 b = *(const float4*)&wfc[off + 4];
            bf16x8 o;
            o[0] = (short)f2bf(a.x); o[1] = (short)f2bf(a.y);
            o[2] = (short)f2bf(a.z); o[3] = (short)f2bf(a.w);
            o[4] = (short)f2bf(b.x); o[5] = (short)f2bf(b.y);
            o[6] = (short)f2bf(b.z); o[7] = (short)f2bf(b.w);
            *(bf16x8*)&wfcb[off] = o;
        }
    } else {
        const int b2 = bid - EW_BLOCKS;        // 0..255
        const int lane = tid & 63;
        const int row = b2 * 4 + (tid >> 6);
        const float* p = wq + (size_t)row * NH + lane * 8;
        float4 a = *(const float4*)p;
        float4 b = *(const float4*)(p + 4);
        bf16x8 o;
        o[0] = (short)f2bf(a.x); o[1] = (short)f2bf(a.y);
        o[2] = (short)f2bf(a.z); o[3] = (short)f2bf(a.w);
        o[4] = (short)f2bf(b.x); o[5] = (short)f2bf(b.y);
        o[6] = (short)f2bf(b.z); o[7] = (short)f2bf(b.w);
        *(bf16x8*)&wqb[(size_t)row * NH + lane * 8] = o;
        float s = a.x*a.x + a.y*a.y + a.z*a.z + a.w*a.w
                + b.x*b.x + b.y*b.y + b.z*b.z + b.w*b.w;
        #pragma unroll
        for (int off = 32; off > 0; off >>= 1) s += __shfl_xor(s, off);
        if (lane == 0) wqsq[row] = s;
        if (tid < 32) hsq[b2 * 32 + tid] = 0.0f;   // zero-init for gemm1 atomics
    }
}

// ---------------- GEMM1: h = relu(xb @ wfcb^T + b) -> bf16 hb, fused hsq ----------------
// R9 post-mortem: 128x128 split-K at 8 waves/CU regressed; R8 (16 waves/CU,
// 2 blocks) is the reference. R10 discriminator: M128xN128, 1024 thr = 16
// waves (4x4 of 32x32) -> SAME wave count as R8, SAME reads/MFMA, NO split-K,
// but 1 block/CU and HALF the A re-reads (4 n-tiles vs 8: A-L3 traffic
// 256->128 MB, B L2-resident). BK=64, 3 bufs, 2-deep counted vmcnt(2)
// (uniform 2 glld16/wave/iter), one barrier/iter:
//   {vmcnt(2) [stage(it) landed] -> s_barrier -> stage(it+2) -> compute(it)}.
// 128-B LDS rows, chunk ^= (row&7) XOR swizzle (pre-swizzled source chunk
// gch8 = (lane&7)^(lane>>3); read ch = ((s*4+quad)^(r&7))*16), <=2-way reads.
__global__ __launch_bounds__(1024, 4) void gemm1_kernel(const unsigned short* __restrict__ xb,
                                                        const unsigned short* __restrict__ wfcb,
                                                        const float* __restrict__ b_fc,
                                                        unsigned short* __restrict__ hb,
                                                        float* __restrict__ hsq) {
    __shared__ unsigned char smem[98304];
    unsigned char* AsB = smem;               // 3 bufs x [128 rows][128 B] = 48 KiB
    unsigned char* BsB = smem + 49152;       // 3 bufs x [128 rows][128 B] = 48 KiB

    const int tid = threadIdx.x;
    const int lane = tid & 63;
    const int wave = tid >> 6;               // 0..15
    const int wm = wave >> 2;                // row block 0..3 (32 rows each)
    const int wn = wave & 3;                 // col block 0..3 (32 cols each)
    const int quad = lane >> 4;
    const int r = lane & 15;
    const int rx = r & 7;

    // bid = c(3b XCD) | q(5b): n-tile = q&3, m-tile = c*8 + (q>>2)
    const int bid = blockIdx.x;              // 0..255
    const int c_ = bid & 7, q_ = bid >> 3;
    const int n0 = (q_ & 3) * 128;
    const int m0 = ((c_ << 3) | (q_ >> 2)) * 128;

    f32x4 acc[2][2];
    #pragma unroll
    for (int i = 0; i < 2; ++i)
        #pragma unroll
        for (int j = 0; j < 2; ++j) acc[i][j] = (f32x4)(0.0f);

    const int lrow8 = lane >> 3;                      // 0..7 (row within 8-row group)
    const int gch8 = (lane & 7) ^ lrow8;              // pre-swizzled 16B source chunk

    const char* asrc = (const char*)xb + (size_t)(m0 + wave * 8 + lrow8) * (NX * 2) + gch8 * 16;
    const char* bsrc = (const char*)wfcb + (size_t)(n0 + wave * 8 + lrow8) * (NX * 2) + gch8 * 16;

    auto stage = [&](int bi, int k0) {                // 2 loads per wave, uniform
        glld16(asrc + (size_t)k0 * 2, AsB + bi * 16384 + wave * 1024);
        glld16(bsrc + (size_t)k0 * 2, BsB + bi * 16384 + wave * 1024);
    };

    stage(0, 0);
    stage(1, 64);

    int cb = 0, sb2 = 2;
    #pragma unroll 1
    for (int it = 0; it < NX / 64; ++it) {            // 32 iters
        if (it == NX / 64 - 1) { asm volatile("s_waitcnt vmcnt(0)" ::: "memory"); }
        else                   { asm volatile("s_waitcnt vmcnt(2)" ::: "memory"); }
        __builtin_amdgcn_sched_barrier(0);
        __builtin_amdgcn_s_barrier();
        __builtin_amdgcn_sched_barrier(0);
        if (it + 2 < NX / 64) stage(sb2, it * 64 + 128);
        __builtin_amdgcn_sched_barrier(0);
        const unsigned char* ab = AsB + cb * 16384;
        const unsigned char* bb = BsB + cb * 16384;
        #pragma unroll
        for (int s = 0; s < 2; ++s) {
            const int ch = ((s * 4 + quad) ^ rx) * 16;
            bf16x8 af[2], bfv[2];
            #pragma unroll
            for (int i = 0; i < 2; ++i)
                af[i] = *(const bf16x8*)(ab + (wm * 32 + i * 16 + r) * 128 + ch);
            #pragma unroll
            for (int j = 0; j < 2; ++j)
                bfv[j] = *(const bf16x8*)(bb + (wn * 32 + j * 16 + r) * 128 + ch);
            #pragma unroll
            for (int i = 0; i < 2; ++i)
                #pragma unroll
                for (int j = 0; j < 2; ++j)
                    acc[i][j] = __builtin_amdgcn_mfma_f32_16x16x32_bf16(af[i], bfv[j], acc[i][j], 0, 0, 0);
        }
        cb = (cb == 2) ? 0 : cb + 1;
        sb2 = (sb2 == 2) ? 0 : sb2 + 1;
    }

    // ---- epilogue: bias + relu -> hb, hsq partial (shuffle + atomic) ----
    float p[2][4];
    #pragma unroll
    for (int i = 0; i < 2; ++i)
        #pragma unroll
        for (int rr = 0; rr < 4; ++rr) p[i][rr] = 0.0f;

    #pragma unroll
    for (int j = 0; j < 2; ++j) {
        int col = n0 + wn * 32 + j * 16 + r;
        float bias = b_fc[col];
        #pragma unroll
        for (int i = 0; i < 2; ++i) {
            int rowb = m0 + wm * 32 + i * 16 + quad * 4;
            #pragma unroll
            for (int rr = 0; rr < 4; ++rr) {
                float v = fmaxf(acc[i][j][rr] + bias, 0.0f);
                hb[(size_t)(rowb + rr) * NH + col] = f2bf(v);
                p[i][rr] += v * v;
            }
        }
    }
    #pragma unroll
    for (int mask = 1; mask < 16; mask <<= 1)
        #pragma unroll
        for (int i = 0; i < 2; ++i)
            #pragma unroll
            for (int rr = 0; rr < 4; ++rr)
                p[i][rr] += __shfl_xor(p[i][rr], mask);
    if (r == 0) {
        #pragma unroll
        for (int i = 0; i < 2; ++i)
            #pragma unroll
            for (int rr = 0; rr < 4; ++rr)
                atomicAdd(&hsq[m0 + wm * 32 + i * 16 + quad * 4 + rr], p[i][rr]);
    }
}

// ---------------- GEMM2 fused with per-row LSE (single pass over out) ----------------
// NU=1  =>  t = -log1p(d)  =>  exp(t) = 1/(1+d): softmax denominator is a v_rcp.
// M=32 x N=1024 (in-block LSE), grid 256 = 1 block/CU. Barrier-free K-loop
// (B staging wave-private, A staged once), 1024 threads = 16 waves = 4
// waves/SIMD, each a private {issue 4 glld16; vmcnt(4); compute} pipeline.
// Wave w owns cols [w*64,+64): acc 2x4. A 32 KiB staged once + B 2x64 KiB.
// s_setprio(1) around the MFMA cluster (T5: waves drift).   [R8 verbatim]
__global__ __launch_bounds__(1024, 4) void gemm2_kernel(const unsigned short* __restrict__ hb,
                                                        const unsigned short* __restrict__ wqb,
                                                        const float* __restrict__ hsq,
                                                        const float* __restrict__ wqsq,
                                                        float* __restrict__ out) {
    __shared__ unsigned char smem[163840];
    char* As = (char*)smem;                  // [16 slabs][32 rows][64 B] = 32 KiB (staged once)
    char* Bs = (char*)smem + 32768;          // [buf][1024 rows][64 B] = 2 x 64 KiB

    const int tid = threadIdx.x;
    const int lane = tid & 63;
    const int wave = tid >> 6;               // 0..15 -> col slab [wave*64, +64)
    const int quad = lane >> 4;
    const int r = lane & 15;
    const int m0 = blockIdx.x * 32;          // 256 blocks

    f32x4 acc[2][4];
    #pragma unroll
    for (int i = 0; i < 2; ++i)
        #pragma unroll
        for (int j = 0; j < 4; ++j) acc[i][j] = (f32x4)(0.0f);

    const int lrow = lane >> 2;                       // 0..15
    const int gch = (lane & 3) ^ ((lrow >> 1) & 3);   // swizzled 16B chunk
    const int fsw = (quad ^ ((r >> 1) & 3)) * 16;

    const char* bsrc = (const char*)wqb + (size_t)(wave * 64 + lrow) * (NH * 2) + gch * 16;

    auto stageB = [&](int buf, int k0) {
        #pragma unroll
        for (int c = 0; c < 4; ++c)                   // this wave's 64 B-rows
            glld16(bsrc + (size_t)(c * 16 * NH + k0) * 2,
                   Bs + buf * 65536 + (wave * 64 + c * 16) * 64);
    };

    // ---- prologue: wave w stages A k-slab w (2 glld16) + its B(0) rows ----
    #pragma unroll
    for (int half = 0; half < 2; ++half)
        glld16((const char*)hb + (size_t)(m0 + half * 16 + lrow) * (NH * 2) + wave * 64 + gch * 16,
               As + wave * 2048 + half * 1024);
    stageB(0, 0);
    asm volatile("s_waitcnt vmcnt(4)" ::: "memory");  // A landed; B(0) may fly
    __builtin_amdgcn_sched_barrier(0);
    __builtin_amdgcn_s_barrier();
    __builtin_amdgcn_sched_barrier(0);

    #pragma unroll 1
    for (int it = 0; it < NH / 32; ++it) {            // 16 iters, NO barriers
        if (it + 1 < NH / 32) stageB((it + 1) & 1, it * 32 + 32);
        __builtin_amdgcn_sched_barrier(0);
        if (it == NH / 32 - 1) { asm volatile("s_waitcnt vmcnt(0)" ::: "memory"); }
        else                   { asm volatile("s_waitcnt vmcnt(4)" ::: "memory"); }
        __builtin_amdgcn_sched_barrier(0);
        const char* ab = As + it * 2048;
        const char* bb = Bs + (it & 1) * 65536;
        bf16x8 af[2], bfv[4];
        #pragma unroll
        for (int i = 0; i < 2; ++i)
            af[i] = *(const bf16x8*)(ab + (i * 16 + r) * 64 + fsw);
        #pragma unroll
        for (int j = 0; j < 4; ++j)
            bfv[j] = *(const bf16x8*)(bb + (wave * 64 + j * 16 + r) * 64 + fsw);
        __builtin_amdgcn_s_setprio(1);
        #pragma unroll
        for (int i = 0; i < 2; ++i)
            #pragma unroll
            for (int j = 0; j < 4; ++j)
                acc[i][j] = __builtin_amdgcn_mfma_f32_16x16x32_bf16(af[i], bfv[j], acc[i][j], 0, 0, 0);
        __builtin_amdgcn_s_setprio(0);
    }

    // ---- epilogue: d, t, row-sums of exp(t) = 1/(1+d), LSE, store ----
    float hs_[2][4];
    #pragma unroll
    for (int i = 0; i < 2; ++i)
        #pragma unroll
        for (int rr = 0; rr < 4; ++rr)
            hs_[i][rr] = hsq[m0 + i * 16 + quad * 4 + rr];

    float srow[2][4];
    #pragma unroll
    for (int i = 0; i < 2; ++i)
        #pragma unroll
        for (int rr = 0; rr < 4; ++rr) srow[i][rr] = 0.0f;

    #pragma unroll
    for (int j = 0; j < 4; ++j) {
        float wqv = wqsq[wave * 64 + j * 16 + r];
        #pragma unroll
        for (int i = 0; i < 2; ++i) {
            #pragma unroll
            for (int rr = 0; rr < 4; ++rr) {
                float d = hs_[i][rr] - 2.0f * acc[i][j][rr] + wqv;
                d = fmaxf(d, 0.0f);
                float onepd = 1.0f + d;
                srow[i][rr] += __builtin_amdgcn_rcpf(onepd);
                acc[i][j][rr] = -__logf(onepd);       // keep t in-register
            }
        }
    }
    #pragma unroll
    for (int mask = 1; mask < 16; mask <<= 1)
        #pragma unroll
        for (int i = 0; i < 2; ++i)
            #pragma unroll
            for (int rr = 0; rr < 4; ++rr)
                srow[i][rr] += __shfl_xor(srow[i][rr], mask);

    float* smemF = (float*)smem;                      // reuse As region
    __syncthreads();                                  // ALL waves out of K-loop first
    if (r == 0) {
        #pragma unroll
        for (int i = 0; i < 2; ++i)
            #pragma unroll
            for (int rr = 0; rr < 4; ++rr)
                smemF[wave * 32 + i * 16 + quad * 4 + rr] = srow[i][rr];
    }
    __syncthreads();
    if (tid < 32) {
        float S = 0.0f;
        #pragma unroll
        for (int w = 0; w < 16; ++w) S += smemF[w * 32 + tid];
        smemF[512 + tid] = __logf(S);
    }
    __syncthreads();

    #pragma unroll
    for (int i = 0; i < 2; ++i) {
        #pragma unroll
        for (int rr = 0; rr < 4; ++rr) {
            float l = smemF[512 + i * 16 + quad * 4 + rr];
            size_t rowoff = (size_t)(m0 + i * 16 + quad * 4 + rr) * NY + wave * 64 + r;
            #pragma unroll
            for (int j = 0; j < 4; ++j)
                out[rowoff + j * 16] = acc[i][j][rr] - l;
        }
    }
}

extern "C" void kernel_launch(void* const* d_in, const int* in_sizes, int n_in,
                              void* d_out, int out_size, void* d_ws, size_t ws_size,
                              hipStream_t stream) {
    const float* x    = (const float*)d_in[0];
    const float* W_fc = (const float*)d_in[1];
    const float* b_fc = (const float*)d_in[2];
    const float* W_q  = (const float*)d_in[3];
    float* out = (float*)d_out;

    char* ws = (char*)d_ws;
    unsigned short* xb   = (unsigned short*)(ws);                        // 32 MiB
    unsigned short* wfcb = (unsigned short*)(ws + 33554432);             // 2 MiB
    unsigned short* wqb  = (unsigned short*)(ws + 35651584);             // 1 MiB
    float*          wqsq = (float*)(ws + 36700160);                      // 4 KiB
    unsigned short* hb   = (unsigned short*)(ws + 36704256);             // 8 MiB
    float*          hsq  = (float*)(ws + 45092864);                      // 32 KiB

    prep_kernel<<<EW_BLOCKS + WQ_BLOCKS, 256, 0, stream>>>(x, W_fc, W_q, xb, wfcb, wqb, wqsq, hsq);
    gemm1_kernel<<<256, 1024, 0, stream>>>(xb, wfcb, b_fc, hb, hsq);
    gemm2_kernel<<<B_ROWS / 32, 1024, 0, stream>>>(hb, wqb, hsq, wqsq, out);
}